// Round 5
// baseline (96.515 us; speedup 1.0000x reference)
//
#include <hip/hip_runtime.h>

#define D 128
#define CAP 48
#define SB 512
#define NREL 24
#define ABLOCKS 2048

// ---------- fast path: capacity CSR + LDS relw + paired float4 gather ----------

__global__ void build_k(const int* __restrict__ head, const int* __restrict__ tail,
                        const int* __restrict__ etype, int* __restrict__ cnt,
                        unsigned* __restrict__ csr, int nE) {
    int i = blockIdx.x * blockDim.x + threadIdx.x;
    if (i < nE) {
        int h = head[i];
        int pos = atomicAdd(&cnt[h], 1);
        if (pos < CAP)
            csr[(size_t)h * CAP + pos] = ((unsigned)tail[i] << 5) | (unsigned)etype[i];
    }
}

// 4 waves/block, persistent; each wave owns a contiguous chunk of entities.
// Within a wave: lanes 0-31 process edge k, lanes 32-63 edge k+1 (same entity),
// each lane holds a float4 slice of the 128-float row.
__global__ void __launch_bounds__(256, 8)
agg4_k(const float* __restrict__ ego, const float* __restrict__ relw,
       const unsigned* __restrict__ csr, const int* __restrict__ cnt,
       float* __restrict__ out, int nEnt) {
    __shared__ float4 lds4[NREL * 32];   // 12 KB

    int tid = threadIdx.x;
    // stage relw into LDS (768 float4 = 3072 floats)
    const float4* __restrict__ rw4 = (const float4*)relw;
    for (int i = tid; i < NREL * 32; i += 256) lds4[i] = rw4[i];
    __syncthreads();

    int gtid = blockIdx.x * 256 + tid;
    int w    = gtid >> 6;                    // global wave id
    int lane = tid & 63;
    int half = lane >> 5;                    // 0: edge k, 1: edge k+1
    int l31  = lane & 31;

    int nwaves = (ABLOCKS * 256) >> 6;       // 8192
    int chunk  = (nEnt + nwaves - 1) / nwaves;
    int e0 = w * chunk;
    int e1 = e0 + chunk; if (e1 > nEnt) e1 = nEnt;

    const float4* __restrict__ ego4 = (const float4*)ego;
    float4* __restrict__ out4 = (float4*)out;

    for (int ent = e0; ent < e1; ++ent) {
        int c = cnt[ent];
        int m = (c < CAP) ? c : CAP;
        const unsigned* __restrict__ row = csr + (size_t)ent * CAP;

        float a0x = 0.f, a0y = 0.f, a0z = 0.f, a0w = 0.f;
        float a1x = 0.f, a1y = 0.f, a1z = 0.f, a1w = 0.f;

        for (int k = 0; k < m; k += 4) {
            uint4 q = *(const uint4*)(row + k);          // 4 csr entries
            unsigned ua = half ? q.y : q.x;
            unsigned ub = half ? q.w : q.z;
            bool va = (k + half) < m;
            bool vb = (k + 2 + half) < m;
            if (va) {
                float4 v = ego4[(int)(ua >> 5) * 32 + l31];
                float4 wv = lds4[(ua & 31u) * 32 + l31];
                a0x += v.x * wv.x; a0y += v.y * wv.y;
                a0z += v.z * wv.z; a0w += v.w * wv.w;
            }
            if (vb) {
                float4 v = ego4[(int)(ub >> 5) * 32 + l31];
                float4 wv = lds4[(ub & 31u) * 32 + l31];
                a1x += v.x * wv.x; a1y += v.y * wv.y;
                a1z += v.z * wv.z; a1w += v.w * wv.w;
            }
        }
        float sx = a0x + a1x, sy = a0y + a1y, sz = a0z + a1z, sw = a0w + a1w;
        // combine the two half-wave partials (lane ^ 32)
        sx += __shfl_xor(sx, 32);
        sy += __shfl_xor(sy, 32);
        sz += __shfl_xor(sz, 32);
        sw += __shfl_xor(sw, 32);
        if (half == 0) {
            float inv = 1.0f / fmaxf((float)c, 1.0f);
            float4 o; o.x = sx * inv; o.y = sy * inv; o.z = sz * inv; o.w = sw * inv;
            out4[(size_t)ent * 32 + l31] = o;
        }
    }
}

// ---------- fallback path (round-2 pipeline, fp32) ----------

__global__ void count_k(const int* __restrict__ head, int* __restrict__ counts, int nE) {
    int i = blockIdx.x * blockDim.x + threadIdx.x;
    if (i < nE) atomicAdd(&counts[head[i]], 1);
}

__global__ void blocksum_k(const int* __restrict__ counts, int* __restrict__ bsum, int nEnt) {
    __shared__ int s[SB];
    int t = threadIdx.x;
    int i = blockIdx.x * SB + t;
    s[t] = (i < nEnt) ? counts[i] : 0;
    __syncthreads();
    for (int off = SB / 2; off > 0; off >>= 1) {
        if (t < off) s[t] += s[t + off];
        __syncthreads();
    }
    if (t == 0) bsum[blockIdx.x] = s[0];
}

__global__ void scanb_k(int* __restrict__ bsum, int nSB) {
    __shared__ int s[SB];
    int t = threadIdx.x;
    int v = (t < nSB) ? bsum[t] : 0;
    s[t] = v;
    __syncthreads();
    for (int off = 1; off < SB; off <<= 1) {
        int x = (t >= off) ? s[t - off] : 0;
        __syncthreads();
        s[t] += x;
        __syncthreads();
    }
    if (t < nSB) bsum[t] = s[t] - v;
}

__global__ void writerows_k(const int* __restrict__ counts, const int* __restrict__ bsum,
                            int* __restrict__ rowstart, int* __restrict__ cursor, int nEnt) {
    __shared__ int s[SB];
    int t = threadIdx.x;
    int i = blockIdx.x * SB + t;
    int v = (i < nEnt) ? counts[i] : 0;
    s[t] = v;
    __syncthreads();
    for (int off = 1; off < SB; off <<= 1) {
        int x = (t >= off) ? s[t - off] : 0;
        __syncthreads();
        s[t] += x;
        __syncthreads();
    }
    if (i < nEnt) {
        int excl = s[t] - v + bsum[blockIdx.x];
        rowstart[i] = excl;
        cursor[i]   = excl;
    }
}

__global__ void bucket_k(const int* __restrict__ head, const int* __restrict__ tail,
                         const int* __restrict__ etype, int* __restrict__ cursor,
                         unsigned* __restrict__ csr, int nE) {
    int i = blockIdx.x * blockDim.x + threadIdx.x;
    if (i < nE) {
        int h = head[i];
        int pos = atomicAdd(&cursor[h], 1);
        csr[pos] = ((unsigned)tail[i] << 5) | (unsigned)etype[i];
    }
}

__global__ void agg_k(const float* __restrict__ ego, const float* __restrict__ relw,
                      const unsigned* __restrict__ csr, const int* __restrict__ rowstart,
                      const int* __restrict__ counts, float* __restrict__ out, int nEnt) {
    int gtid = blockIdx.x * blockDim.x + threadIdx.x;
    int wid  = gtid >> 6;
    int lane = gtid & 63;
    if (wid >= nEnt) return;
    int rs = __builtin_amdgcn_readfirstlane(rowstart[wid]);
    int c  = __builtin_amdgcn_readfirstlane(counts[wid]);
    const float2* __restrict__ ego2 = (const float2*)ego;
    const float2* __restrict__ rw2  = (const float2*)relw;
    float2 acc; acc.x = 0.f; acc.y = 0.f;
    unsigned u = (c > 0) ? csr[rs] : 0u;
    for (int k = 0; k < c; ++k) {
        unsigned un = (k + 1 < c) ? csr[rs + k + 1] : 0u;
        int t = (int)(u >> 5);
        int r = (int)(u & 31u);
        float2 v = ego2[(size_t)t * 64 + lane];
        float2 w = rw2[(size_t)r * 64 + lane];
        acc.x += v.x * w.x;
        acc.y += v.y * w.y;
        u = un;
    }
    float inv = 1.0f / fmaxf((float)c, 1.0f);
    float2 o; o.x = acc.x * inv; o.y = acc.y * inv;
    ((float2*)out)[(size_t)wid * 64 + lane] = o;
}

extern "C" void kernel_launch(void* const* d_in, const int* in_sizes, int n_in,
                              void* d_out, int out_size, void* d_ws, size_t ws_size,
                              hipStream_t stream) {
    const float* ego   = (const float*)d_in[0];
    const int*   eidx  = (const int*)d_in[1];
    const int*   etype = (const int*)d_in[2];
    const float* relw  = (const float*)d_in[3];
    float* out = (float*)d_out;

    int nE   = in_sizes[2];        // 600000
    int nEnt = in_sizes[0] / D;    // 100000
    const int* head = eidx;
    const int* tail = eidx + nE;

    char* ws = (char*)d_ws;
    size_t cntB = (size_t)nEnt * 4;          // 400 KB
    size_t csrB = (size_t)nEnt * CAP * 4;    // 19.2 MB
    size_t needFast = cntB + csrB;

    int eblocks = (nE + 255) / 256;

    if (ws_size >= needFast) {
        int*      cnt = (int*)ws;
        unsigned* csr = (unsigned*)(ws + cntB);

        hipMemsetAsync(cnt, 0, cntB, stream);
        build_k<<<eblocks, 256, 0, stream>>>(head, tail, etype, cnt, csr, nE);
        agg4_k<<<ABLOCKS, 256, 0, stream>>>(ego, relw, csr, cnt, out, nEnt);
    } else {
        int nSB = (nEnt + SB - 1) / SB;
        int*      counts   = (int*)ws;
        int*      rowstart = (int*)(ws + cntB);
        int*      cursor   = (int*)(ws + cntB * 2);
        int*      bsum     = (int*)(ws + cntB * 3);
        unsigned* csr      = (unsigned*)(ws + cntB * 3 + SB * 4);

        int ablocks = (int)(((size_t)nEnt * 64 + 255) / 256);
        hipMemsetAsync(counts, 0, cntB, stream);
        count_k<<<eblocks, 256, 0, stream>>>(head, counts, nE);
        blocksum_k<<<nSB, SB, 0, stream>>>(counts, bsum, nEnt);
        scanb_k<<<1, SB, 0, stream>>>(bsum, nSB);
        writerows_k<<<nSB, SB, 0, stream>>>(counts, bsum, rowstart, cursor, nEnt);
        bucket_k<<<eblocks, 256, 0, stream>>>(head, tail, etype, cursor, csr, nE);
        agg_k<<<ablocks, 256, 0, stream>>>(ego, relw, csr, rowstart, counts, out, nEnt);
    }
}